// Round 15
// baseline (92.488 us; speedup 1.0000x reference)
//
#include <hip/hip_runtime.h>

namespace {
constexpr int NB  = 131072;
constexpr int NJ  = 24;
constexpr int PAR[NJ] = {0,0,0,0,1,2,3,4,5,6,7,8,9,9,9,12,13,14,16,17,18,19,20,21};
constexpr int BLK = 64;          // one wave per block
constexpr int BPB = 32;          // batches per block (2 lanes per batch)
constexpr int QS  = 17;          // f4 stride/batch, oT stage (16 data + 1 pad)
constexpr int PSF = 28;          // float stride/batch, oP stage (24 data + 4 pad)
constexpr int LDSF4 = BPB * QS;  // 544 f4 = 8704 B -> 16 blocks/CU fits 139 KB
}

typedef float f32x4 __attribute__((ext_vector_type(4)));

// Midpoint of the TLP-vs-replication tradeoff: r8 = {64 batches/wave, 1x load
// replication, 8 waves/CU} = 66.7us; r14 = {16 b/w, 4x repl, ~15 w/CU} = 77.8us.
// This: 32 batches/wave, 2x repl, 16 waves/CU. Lane h in {0,1} owns rows
// {2h, 2h+1} of every global transform (row recurrence is row-independent;
// row 3 = [0,0,0,1] rides the same code as constants). h enters only as
// init-time selects, never an index -> no scratch, no divergence. Output
// paths = the measured-clean shapes: oT per-quad LDS transpose + full-line
// nt stores, oP per-group stage + nt (r12 A/B: nt = +38%). Zero barriers.
__global__ __launch_bounds__(BLK, 4) void pose_kernel(
    const float* __restrict__ rot,
    const float* __restrict__ pos,
    float* __restrict__ outT,
    float* __restrict__ outP)
{
    __shared__ __align__(16) f32x4 lds[LDSF4];
    float* ldsf = reinterpret_cast<float*>(lds);

    const int t  = threadIdx.x;
    const int h  = t & 1;           // row-pair selector: rows {2h, 2h+1}
    const int bl = t >> 1;          // local batch 0..31
    const int b0 = blockIdx.x * BPB;
    const int b  = b0 + bl;

    const float* prow = pos + (size_t)b * 72;
    const float* rrow = rot + (size_t)b * 216;
    const bool h0 = (h == 0);

    float rowsA[NJ][3];  // my first row (0 or 2) of each global rotation
    float rowsB[NJ][3];  // my second row (1 or 3==const) of each global rotation
    float tgA[NJ];       // my first row's translation component
    float tgB[NJ];       // my second row's translation component
    float carry1[9];     // pos of joints 5,6,7  (needed in group 1)
    float carry2[6];     // pos of joints 13,14  (needed in group 2)
    float Pg[24];        // current group's positions (replicated per lane pair)

    #pragma unroll
    for (int g = 0; g < 3; ++g) {
        // ---- group positions: 6 f4 loads (same addr within lane pair) ----
        #pragma unroll
        for (int i = 0; i < 6; ++i) {
            f32x4 v = *reinterpret_cast<const f32x4*>(prow + 24 * g + 4 * i);
            Pg[4*i+0] = v.x; Pg[4*i+1] = v.y; Pg[4*i+2] = v.z; Pg[4*i+3] = v.w;
        }

        #pragma unroll
        for (int q = 0; q < 2; ++q) {          // quad of 4 joints
            // ---- rot for this quad: 9 f4 loads (2x replicated, 32 lines/instr) ----
            float buf[36];
            #pragma unroll
            for (int i = 0; i < 9; ++i) {
                f32x4 v = *reinterpret_cast<const f32x4*>(rrow + 72 * g + 36 * q + 4 * i);
                buf[4*i+0] = v.x; buf[4*i+1] = v.y; buf[4*i+2] = v.z; buf[4*i+3] = v.w;
            }

            #pragma unroll
            for (int l = 0; l < 4; ++l) {
                const int j  = 8 * g + 4 * q + l;
                const int pj = PAR[j];
                const float* L = buf + 9 * l;   // static offset
                const int lj = 3 * j - 24 * g;  // this joint's pos within Pg

                if (j == 0) {
                    #pragma unroll
                    for (int k = 0; k < 3; ++k) {
                        rowsA[0][k] = h0 ? L[k]   : L[6+k];  // row 0 : row 2
                        rowsB[0][k] = h0 ? L[3+k] : 0.0f;    // row 1 : row 3
                    }
                    tgA[0] = h0 ? Pg[0] : Pg[2];
                    tgB[0] = h0 ? Pg[1] : 1.0f;
                } else {
                    float pxp, pyp, pzp;
                    if (pj >= 8 * g) {                  // parent in this group
                        const int lp = 3 * pj - 24 * g;
                        pxp = Pg[lp]; pyp = Pg[lp+1]; pzp = Pg[lp+2];
                    } else if (g == 1) {                // parent in {5,6,7}
                        const int ci = 3 * (pj - 5);
                        pxp = carry1[ci]; pyp = carry1[ci+1]; pzp = carry1[ci+2];
                    } else {                            // g==2, parent in {13,14}
                        const int ci = 3 * (pj - 13);
                        pxp = carry2[ci]; pyp = carry2[ci+1]; pzp = carry2[ci+2];
                    }
                    const float relx = Pg[lj]   - pxp;
                    const float rely = Pg[lj+1] - pyp;
                    const float relz = Pg[lj+2] - pzp;
                    #pragma unroll
                    for (int c = 0; c < 3; ++c) {
                        rowsA[j][c] = rowsA[pj][0] * L[c]
                                    + rowsA[pj][1] * L[3+c]
                                    + rowsA[pj][2] * L[6+c];
                        rowsB[j][c] = rowsB[pj][0] * L[c]
                                    + rowsB[pj][1] * L[3+c]
                                    + rowsB[pj][2] * L[6+c];
                    }
                    tgA[j] = rowsA[pj][0] * relx + rowsA[pj][1] * rely
                           + rowsA[pj][2] * relz + tgA[pj];
                    tgB[j] = rowsB[pj][0] * relx + rowsB[pj][1] * rely
                           + rowsB[pj][2] * relz + tgB[pj];
                }

                // ---- stage my two oT rows of this joint into LDS ----
                const float px = Pg[lj], py = Pg[lj+1], pz = Pg[lj+2];
                const float ibA = rowsA[j][0]*px + rowsA[j][1]*py + rowsA[j][2]*pz;
                const float ibB = rowsB[j][0]*px + rowsB[j][1]*py + rowsB[j][2]*pz;
                lds[bl * QS + l * 4 + 2 * h + 0] =
                    f32x4{rowsA[j][0], rowsA[j][1], rowsA[j][2], tgA[j] - ibA};
                lds[bl * QS + l * 4 + 2 * h + 1] =
                    f32x4{rowsB[j][0], rowsB[j][1], rowsB[j][2], tgB[j] - ibB};
            }

            // ---- oT quad: coalesced nt write (512 f4 = 8 instrs/wave) ----
            {
                float* gp = outT + (size_t)b0 * 384 + (8 * g + 4 * q) * 16;
                #pragma unroll
                for (int i = 0; i < 8; ++i) {
                    int f = t + BLK * i;          // 512 f4 = 32 batches x 16
                    int br = f >> 4, col = f & 15;
                    f32x4 v = lds[br * QS + col];
                    __builtin_nontemporal_store(
                        v, reinterpret_cast<f32x4*>(gp + (size_t)br * 384 + col * 4));
                }
            }
        }

        // ---- oP for this group: stage 8 joints' tg components, nt write ----
        #pragma unroll
        for (int jl = 0; jl < 8; ++jl) {
            const int j = 8 * g + jl;
            ldsf[bl * PSF + jl * 3 + 2 * h] = tgA[j];      // row 0 or row 2
            if (h0) ldsf[bl * PSF + jl * 3 + 1] = tgB[j];  // row 1
        }
        {
            float* gp = outP + (size_t)b0 * 72 + g * 24;
            #pragma unroll
            for (int i = 0; i < 3; ++i) {
                int f = t + BLK * i;              // 192 f4 = 32 batches x 6
                int br = f / 6, col = f % 6;
                f32x4 v = *reinterpret_cast<const f32x4*>(&ldsf[br * PSF + col * 4]);
                __builtin_nontemporal_store(
                    v, reinterpret_cast<f32x4*>(gp + (size_t)br * 72 + col * 4));
            }
        }

        // ---- save cross-group parent positions (static) ----
        if (g == 0) {
            #pragma unroll
            for (int k = 0; k < 9; ++k) carry1[k] = Pg[15 + k];   // joints 5,6,7
        } else if (g == 1) {
            #pragma unroll
            for (int k = 0; k < 6; ++k) carry2[k] = Pg[15 + k];   // joints 13,14
        }
    }
}

extern "C" void kernel_launch(void* const* d_in, const int* in_sizes, int n_in,
                              void* d_out, int out_size, void* d_ws, size_t ws_size,
                              hipStream_t stream) {
    const float* rot = (const float*)d_in[0];
    const float* pos = (const float*)d_in[1];
    float* outT = (float*)d_out;
    float* outP = outT + (size_t)NB * NJ * 16;
    dim3 grid(NB / BPB), block(BLK);
    hipLaunchKernelGGL(pose_kernel, grid, block, 0, stream, rot, pos, outT, outP);
}

// Round 16
// 66.611 us; speedup vs baseline: 1.3885x; 1.3885x over previous
//
#include <hip/hip_runtime.h>

namespace {
constexpr int NB  = 131072;
constexpr int NJ  = 24;
constexpr int PAR[NJ] = {0,0,0,0,1,2,3,4,5,6,7,8,9,9,9,12,13,14,16,17,18,19,20,21};
constexpr int BLK = 64;         // one wave per block; batches per block
constexpr int SOT = 68;         // LDS row stride (floats) oT staging (64 data + 4 pad)
constexpr int SPO = 76;         // LDS row stride (floats) oP staging (72 data + 4 pad)
constexpr int LDSF = BLK * SPO; // 19456 B -> 8 blocks/CU
}

typedef float f32x4 __attribute__((ext_vector_type(4)));

// CHAMPION (round 8, 66.7us): single-wave blocks, ZERO barriers, direct
// per-lane input loads (fine-grained dependency chains; coarse LDS staging
// measured worse), LDS only for output transposes, nontemporal stores
// (measured +38% vs plain in round 12's A/B). 8 waves/CU, grid-capped.
__global__ __launch_bounds__(BLK) void pose_kernel(
    const float* __restrict__ rot,
    const float* __restrict__ pos,
    float* __restrict__ outT,
    float* __restrict__ outP)
{
    __shared__ __align__(16) float lds[LDSF];
    const int t  = threadIdx.x;   // 0..63, lane == batch within block
    const int b0 = blockIdx.x * BLK;

    const float* prow = pos + (size_t)(b0 + t) * 72;   // this thread's pos row
    const float* rrow = rot + (size_t)(b0 + t) * 216;  // this thread's rot row

    float Rg[NJ][9];
    float tg[NJ][3];
    float carry1[9];   // P of joints 5,6,7   (needed by group 1)
    float carry2[6];   // P of joints 13,14   (needed by group 2)

    #pragma unroll
    for (int g = 0; g < 3; ++g) {
        // ---- group-local positions: joints 8g..8g+7 = floats [24g, 24g+24) ----
        float Pg[24];
        #pragma unroll
        for (int i = 0; i < 6; ++i) {
            f32x4 v = *reinterpret_cast<const f32x4*>(prow + 24 * g + 4 * i);
            Pg[4*i+0] = v.x; Pg[4*i+1] = v.y; Pg[4*i+2] = v.z; Pg[4*i+3] = v.w;
        }

        #pragma unroll
        for (int q = 0; q < 2; ++q) {           // quad = 4 joints
            // ---- direct rot loads: floats [72g+36q, +36) of this row ----
            float buf[36];
            #pragma unroll
            for (int i = 0; i < 9; ++i) {
                f32x4 v = *reinterpret_cast<const f32x4*>(rrow + 72 * g + 36 * q + 4 * i);
                buf[4*i+0] = v.x; buf[4*i+1] = v.y; buf[4*i+2] = v.z; buf[4*i+3] = v.w;
            }

            // ---- compute 4 joints (parent always < j; all indices static) ----
            #pragma unroll
            for (int l = 0; l < 4; ++l) {
                const int j  = 8 * g + 4 * q + l;
                const int pj = PAR[j];
                float L[9];
                #pragma unroll
                for (int k = 0; k < 9; ++k) L[k] = buf[9 * (4 * q + l) - 36 * q + k];

                if (j == 0) {
                    #pragma unroll
                    for (int k = 0; k < 9; ++k) Rg[0][k] = L[k];
                    tg[0][0] = Pg[0]; tg[0][1] = Pg[1]; tg[0][2] = Pg[2];
                } else {
                    float pxp, pyp, pzp;
                    if (pj >= 8 * g) {                 // parent in this group
                        const int lp = 3 * pj - 24 * g;
                        pxp = Pg[lp]; pyp = Pg[lp+1]; pzp = Pg[lp+2];
                    } else if (g == 1) {               // parent in {5,6,7}
                        const int ci = 3 * (pj - 5);
                        pxp = carry1[ci]; pyp = carry1[ci+1]; pzp = carry1[ci+2];
                    } else {                           // g==2, parent in {13,14}
                        const int ci = 3 * (pj - 13);
                        pxp = carry2[ci]; pyp = carry2[ci+1]; pzp = carry2[ci+2];
                    }
                    const int lj = 3 * j - 24 * g;
                    float rel[3] = { Pg[lj] - pxp, Pg[lj+1] - pyp, Pg[lj+2] - pzp };
                    #pragma unroll
                    for (int r = 0; r < 3; ++r) {
                        #pragma unroll
                        for (int c = 0; c < 3; ++c) {
                            Rg[j][3*r+c] = Rg[pj][3*r+0] * L[0+c]
                                         + Rg[pj][3*r+1] * L[3+c]
                                         + Rg[pj][3*r+2] * L[6+c];
                        }
                        tg[j][r] = Rg[pj][3*r+0] * rel[0]
                                 + Rg[pj][3*r+1] * rel[1]
                                 + Rg[pj][3*r+2] * rel[2]
                                 + tg[pj][r];
                    }
                }
            }

            // ---- oT: stage this quad (64 floats/row) then coalesced nt write ----
            #pragma unroll
            for (int l = 0; l < 4; ++l) {
                const int j  = 8 * g + 4 * q + l;
                const int lj = 3 * j - 24 * g;
                float px = Pg[lj], py = Pg[lj+1], pz = Pg[lj+2];
                #pragma unroll
                for (int r = 0; r < 3; ++r) {
                    float ib = Rg[j][3*r]*px + Rg[j][3*r+1]*py + Rg[j][3*r+2]*pz;
                    *reinterpret_cast<f32x4*>(&lds[t * SOT + (l*4 + r) * 4]) =
                        f32x4{Rg[j][3*r], Rg[j][3*r+1], Rg[j][3*r+2], tg[j][r] - ib};
                }
                *reinterpret_cast<f32x4*>(&lds[t * SOT + (l*4 + 3) * 4]) =
                    f32x4{0.f, 0.f, 0.f, 1.f};
            }
            {
                float* gp = outT + (size_t)b0 * 384 + (8 * g + 4 * q) * 16;
                #pragma unroll
                for (int i = 0; i < 16; ++i) {
                    int f = t + BLK * i;          // 1024 f4 = 64 rows x 16
                    int row = f >> 4, col = f & 15;
                    f32x4 v = *reinterpret_cast<const f32x4*>(&lds[row * SOT + col * 4]);
                    __builtin_nontemporal_store(
                        v, reinterpret_cast<f32x4*>(gp + (size_t)row * 384 + col * 4));
                }
            }
        }

        // ---- save cross-group parent positions (all static) ----
        if (g == 0) {
            #pragma unroll
            for (int k = 0; k < 9; ++k) carry1[k] = Pg[15 + k];   // joints 5,6,7
        } else if (g == 1) {
            #pragma unroll
            for (int k = 0; k < 6; ++k) carry2[k] = Pg[15 + k];   // joints 13,14
        }
    }

    // ---- oP: stage all 24 translations (72 floats/row), coalesced nt write ----
    #pragma unroll
    for (int i = 0; i < 18; ++i) {
        float vals[4];
        #pragma unroll
        for (int k = 0; k < 4; ++k) {
            int e = 4*i + k;                  // 0..71, static
            vals[k] = tg[e / 3][e % 3];
        }
        *reinterpret_cast<f32x4*>(&lds[t * SPO + i * 4]) =
            f32x4{vals[0], vals[1], vals[2], vals[3]};
    }
    {
        float* gp = outP + (size_t)b0 * 72;
        #pragma unroll
        for (int i = 0; i < 18; ++i) {
            int f = t + BLK * i;              // 1152 f4 = 64 rows x 18
            int row = f / 18, col = f % 18;
            f32x4 v = *reinterpret_cast<const f32x4*>(&lds[row * SPO + col * 4]);
            __builtin_nontemporal_store(
                v, reinterpret_cast<f32x4*>(gp + (size_t)row * 72 + col * 4));
        }
    }
}

extern "C" void kernel_launch(void* const* d_in, const int* in_sizes, int n_in,
                              void* d_out, int out_size, void* d_ws, size_t ws_size,
                              hipStream_t stream) {
    const float* rot = (const float*)d_in[0];
    const float* pos = (const float*)d_in[1];
    float* outT = (float*)d_out;
    float* outP = outT + (size_t)NB * NJ * 16;
    dim3 grid(NB / BLK), block(BLK);
    hipLaunchKernelGGL(pose_kernel, grid, block, 0, stream, rot, pos, outT, outP);
}